// Round 4
// baseline (725.568 us; speedup 1.0000x reference)
//
#include <hip/hip_runtime.h>

// Sparse conv via (bucket,k) binning + per-k MFMA tiles + LDS f32 scatter-accumulate.
// N=262144, M=131072 (2^17), K=27, C_in=C_out=32. fp32 in/out, f16 internal (MFMA).
//
// Pipeline:
//   0. memset gcur=0
//   1. convert: input f32 -> f16 rows (64B/row)
//   2. wprep:   kernel f32 -> f16 B-fragments of mfma_f32_16x16x32_f16
//   3. bin:     entries scattered to sub-buckets [bucket=out>>10][k], payload (in<<10)|(out&1023)
//   4. compute: 1 block/bucket: per k, 16-entry MFMA tiles (W_k in VGPRs),
//               C-frags ds_add_f32 into LDS acc[1024][32], bias-fused coalesced store.

constexpr int N_VOX   = 262144;
constexpr int M_PAIRS = 131072;
constexpr int K_VOL   = 27;
constexpr int E_TOT   = K_VOL * M_PAIRS;   // 3538944
constexpr int NB      = 256;               // buckets
constexpr int ROWS    = 1024;              // output rows per bucket
constexpr int SCAP    = 640;               // sub-bucket capacity (mean 512, sigma 22.6, +5.7σ)

typedef _Float16 h2  __attribute__((ext_vector_type(2)));
typedef _Float16 h8  __attribute__((ext_vector_type(8)));
typedef float    f32x4 __attribute__((ext_vector_type(4)));

// ---- workspace layout (bytes) ----
constexpr size_t WS_GCUR = 0;                      // int[NB*27] = 27648 B
constexpr size_t WS_WB   = 64 * 1024;              // f16[27][2][64][8] = 55296 B
constexpr size_t WS_HIN  = (size_t)1 << 20;        // ushort[N*32] : 16 MB
constexpr size_t WS_SUB  = (size_t)17 << 20;       // int[NB*27*SCAP] : 17.7 MB
// total ~35 MB

// Phase 1: input f32 -> f16. 8 floats/thread, exact grid 4096x256.
__global__ __launch_bounds__(256) void convert_kernel(const float* __restrict__ in,
                                                      uint4* __restrict__ hin4) {
    const int idx = blockIdx.x * 256 + threadIdx.x;   // 0 .. 2^20-1
    const float4* in4 = (const float4*)in;
    const float4 a = in4[2 * idx];
    const float4 b = in4[2 * idx + 1];
    h2 p0; p0[0] = (_Float16)a.x; p0[1] = (_Float16)a.y;
    h2 p1; p1[0] = (_Float16)a.z; p1[1] = (_Float16)a.w;
    h2 p2; p2[0] = (_Float16)b.x; p2[1] = (_Float16)b.y;
    h2 p3; p3[0] = (_Float16)b.z; p3[1] = (_Float16)b.w;
    uint4 v;
    v.x = __builtin_bit_cast(unsigned, p0);
    v.y = __builtin_bit_cast(unsigned, p1);
    v.z = __builtin_bit_cast(unsigned, p2);
    v.w = __builtin_bit_cast(unsigned, p3);
    hin4[idx] = v;
}

// Phase 2: B-fragment prep. WB[k][nt][lane][q] = f16(W_k[8*(lane>>4)+q][nt*16+(lane&15)]).
// 27*2*64*8 = 27648 values; grid 108x256.
__global__ __launch_bounds__(256) void wprep_kernel(const float* __restrict__ kern,
                                                    unsigned short* __restrict__ wb) {
    const int idx = blockIdx.x * 256 + threadIdx.x;   // 0..27647
    const int q  = idx & 7;
    const int l  = (idx >> 3) & 63;
    const int nt = (idx >> 9) & 1;
    const int k  = idx >> 10;
    const int kin = 8 * (l >> 4) + q;       // 0..31 (B row = input channel)
    const int col = nt * 16 + (l & 15);     // 0..31 (B col = output channel)
    const float w = kern[k * 1024 + kin * 32 + col];
    wb[idx] = __builtin_bit_cast(unsigned short, (_Float16)w);
}

// Phase 3: bin entries into sub-buckets. 864 blocks x 256 thr, 16 entries/thread.
// Each block covers 4096 consecutive entries -> single k (4096 | 131072).
__global__ __launch_bounds__(256) void bin_kernel(const int* __restrict__ in_map,
                                                  const int* __restrict__ out_map,
                                                  int* __restrict__ gcur,
                                                  int* __restrict__ subbuf) {
    __shared__ int lh[NB];      // histogram, then cursor
    __shared__ int pad_unused;  // (keep layout simple)
    const int t = threadIdx.x;
    lh[t] = 0;                  // blockDim == NB == 256
    __syncthreads();

    const int k = (blockIdx.x * 4096) >> 17;
    int4 ivv[4], ovv[4];
    #pragma unroll
    for (int j = 0; j < 4; ++j) {
        const int i4 = blockIdx.x * 1024 + j * 256 + t;
        ivv[j] = ((const int4*)in_map)[i4];
        ovv[j] = ((const int4*)out_map)[i4];
    }
    #pragma unroll
    for (int j = 0; j < 4; ++j) {
        atomicAdd(&lh[ovv[j].x >> 10], 1);
        atomicAdd(&lh[ovv[j].y >> 10], 1);
        atomicAdd(&lh[ovv[j].z >> 10], 1);
        atomicAdd(&lh[ovv[j].w >> 10], 1);
    }
    __syncthreads();
    {
        const int c = lh[t];
        int base = 0;
        if (c > 0) base = atomicAdd(&gcur[t * K_VOL + k], c);
        __syncthreads();          // all hist reads done before reuse
        lh[t] = base;             // becomes cursor
    }
    __syncthreads();

    #pragma unroll
    for (int j = 0; j < 4; ++j) {
        int4 I = ivv[j], O = ovv[j];
        {
            const int b = O.x >> 10, p = (I.x << 10) | (O.x & 1023);
            const int pos = atomicAdd(&lh[b], 1);
            if (pos < SCAP) subbuf[(b * K_VOL + k) * SCAP + pos] = p;
        }
        {
            const int b = O.y >> 10, p = (I.y << 10) | (O.y & 1023);
            const int pos = atomicAdd(&lh[b], 1);
            if (pos < SCAP) subbuf[(b * K_VOL + k) * SCAP + pos] = p;
        }
        {
            const int b = O.z >> 10, p = (I.z << 10) | (O.z & 1023);
            const int pos = atomicAdd(&lh[b], 1);
            if (pos < SCAP) subbuf[(b * K_VOL + k) * SCAP + pos] = p;
        }
        {
            const int b = O.w >> 10, p = (I.w << 10) | (O.w & 1023);
            const int pos = atomicAdd(&lh[b], 1);
            if (pos < SCAP) subbuf[(b * K_VOL + k) * SCAP + pos] = p;
        }
    }
}

// Phase 4: compute. 256 blocks (1/bucket) x 1024 threads (16 waves).
// LDS: acc[(ROWS+1)][33] f32 = 135300 B (row stride 33 kills ds_add bank aliasing;
// row ROWS is the dump row for tail lanes).
__global__ __launch_bounds__(1024, 4) void compute_kernel(
    const unsigned short* __restrict__ hin,
    const unsigned short* __restrict__ wb,
    const float* __restrict__ bias,
    const int*  __restrict__ gcur,
    const int*  __restrict__ subbuf,
    float* __restrict__ out)
{
    __shared__ float acc[(ROWS + 1) * 33];   // 135300 B

    const int t = threadIdx.x;
    for (int i = t; i < (ROWS + 1) * 33; i += 1024) acc[i] = 0.f;
    __syncthreads();

    const int b      = blockIdx.x;
    const int l      = t & 63;
    const int wave   = t >> 6;       // 0..15
    const int lane16 = l & 15;
    const int seg    = l >> 4;       // 0..3

    const uint4* wbu = (const uint4*)wb;

    for (int k = 0; k < K_VOL; ++k) {
        const int nk_raw = gcur[b * K_VOL + k];
        const int nk = (nk_raw < SCAP) ? nk_raw : SCAP;
        if (nk == 0) continue;
        const int T = (nk + 15) >> 4;
        const int* sb = subbuf + (b * K_VOL + k) * SCAP;

        // B-fragments for W_k (8 VGPRs), reused for all tiles of this k.
        const uint4* wp = wbu + (k * 2) * 64 + l;
        const h8 B0 = __builtin_bit_cast(h8, wp[0]);
        const h8 B1 = __builtin_bit_cast(h8, wp[64]);

        for (int tt = wave; tt < T; tt += 16) {
            const int idx   = tt * 16 + lane16;
            const bool valid = (idx < nk);
            const int e  = sb[valid ? idx : 0];
            const int in_row = valid ? (e >> 10) : 0;
            const int lr     = valid ? (e & 1023) : ROWS;   // tail -> dump row

            // A-fragment: row (l&15) of the tile = gathered input row, k-chunk seg*8..+7.
            const uint4 a4 = *(const uint4*)(hin + (size_t)in_row * 32 + seg * 8);
            const h8 A = __builtin_bit_cast(h8, a4);

            f32x4 c0 = {0.f, 0.f, 0.f, 0.f};
            f32x4 c1 = {0.f, 0.f, 0.f, 0.f};
            c0 = __builtin_amdgcn_mfma_f32_16x16x32_f16(A, B0, c0, 0, 0, 0);
            c1 = __builtin_amdgcn_mfma_f32_16x16x32_f16(A, B1, c1, 0, 0, 0);

            // C/D: col = lane&15, row = (lane>>4)*4 + r. Scatter-add into LDS acc.
            #pragma unroll
            for (int r = 0; r < 4; ++r) {
                const int lre = __shfl(lr, seg * 4 + r, 64);  // lr of entry (seg*4+r)
                const int addr = lre * 33 + lane16;
                atomicAdd(&acc[addr], c0[r]);
                atomicAdd(&acc[addr + 16], c1[r]);
            }
        }
    }
    __syncthreads();

    // Bias-fused coalesced store of the bucket's 1024 rows.
    for (int i = t; i < ROWS * 32; i += 1024) {
        const int lr = i >> 5;
        const int c  = i & 31;
        out[(size_t)(((b << 10) | lr)) * 32 + c] = acc[lr * 33 + c] + bias[c];
    }
}

extern "C" void kernel_launch(void* const* d_in, const int* in_sizes, int n_in,
                              void* d_out, int out_size, void* d_ws, size_t ws_size,
                              hipStream_t stream) {
    const float* input   = (const float*)d_in[0];
    const float* kernel  = (const float*)d_in[1];
    const float* bias    = (const float*)d_in[2];
    const int*   in_map  = (const int*)d_in[3];
    const int*   out_map = (const int*)d_in[4];
    float* out = (float*)d_out;

    char* ws = (char*)d_ws;
    int* gcur            = (int*)(ws + WS_GCUR);
    unsigned short* wbuf = (unsigned short*)(ws + WS_WB);
    unsigned short* hin  = (unsigned short*)(ws + WS_HIN);
    int* subbuf          = (int*)(ws + WS_SUB);

    hipMemsetAsync(gcur, 0, NB * K_VOL * sizeof(int), stream);
    convert_kernel<<<4096, 256, 0, stream>>>(input, (uint4*)hin);
    wprep_kernel  <<<108,  256, 0, stream>>>(kernel, wbuf);
    bin_kernel    <<<E_TOT / 4096, 256, 0, stream>>>(in_map, out_map, gcur, subbuf);
    compute_kernel<<<NB, 1024, 0, stream>>>(hin, wbuf, bias, gcur, subbuf, out);
}

// Round 6
// 242.720 us; speedup vs baseline: 2.9893x; 2.9893x over previous
//
#include <hip/hip_runtime.h>

// Sparse conv, atomic-free compute:
//   bin entries by (bucket=out>>10, k)  ->  per-64-row-window blocks, per-16-row waves:
//   A-tile = 16 gathered f16 input rows; C_e = A @ W_k (2x mfma_16x16x32_f16);
//   scatter = acc += P @ f16(C_e) (mfma_16x16x16f16, P = 0/1 row-assignment matrix).
//   Accumulator lives in registers for all 27 k; single coalesced store + bias.
// N=262144, M=131072 (2^17), K=27, C_in=C_out=32. fp32 in/out, f16 internal.

constexpr int N_VOX   = 262144;
constexpr int M_PAIRS = 131072;
constexpr int K_VOL   = 27;
constexpr int E_TOT   = K_VOL * M_PAIRS;   // 3538944
constexpr int NB      = 256;               // bin buckets (1024 out-rows each)
constexpr int SCAP    = 640;               // per-(bucket,k) capacity (mean 512)
constexpr int SUBCAP  = 48;                // per-(16-row,k) capacity (mean 8)

typedef _Float16 h2  __attribute__((ext_vector_type(2)));
typedef _Float16 h4  __attribute__((ext_vector_type(4)));
typedef _Float16 h8  __attribute__((ext_vector_type(8)));
typedef float    f32x4 __attribute__((ext_vector_type(4)));

// ---- workspace layout (bytes) ----
constexpr size_t WS_GCUR = 0;                      // int[NB*27] = 27648 B
constexpr size_t WS_WB   = 64 * 1024;              // f16 B-frags: 27*2*64*8 = 55296 B
constexpr size_t WS_HIN  = (size_t)1 << 20;        // ushort[(N+16)*32] : 16 MB + zero row
constexpr size_t WS_SUB  = (size_t)18 << 20;       // int[NB*27*SCAP] : 17.7 MB
// total ~35.7 MB

__device__ inline f32x4 mfma16x16x32(h8 a, h8 b, f32x4 c) {
    return __builtin_amdgcn_mfma_f32_16x16x32_f16(a, b, c, 0, 0, 0);
}
__device__ inline f32x4 mfma16x16x16(h4 a, h4 b, f32x4 c) {
    return __builtin_amdgcn_mfma_f32_16x16x16f16(a, b, c, 0, 0, 0);
}

// Phase 1: input f32 -> f16 rows; block 4096 writes the zero row (index N_VOX).
__global__ __launch_bounds__(256) void convert_kernel(const float* __restrict__ in,
                                                      uint4* __restrict__ hin4) {
    if (blockIdx.x == 4096) {
        if (threadIdx.x < 4) hin4[(1u << 20) + threadIdx.x] = (uint4){0, 0, 0, 0};
        return;
    }
    const int idx = blockIdx.x * 256 + threadIdx.x;   // 0 .. 2^20-1
    const float4* in4 = (const float4*)in;
    const float4 a = in4[2 * idx];
    const float4 b = in4[2 * idx + 1];
    h2 p0; p0[0] = (_Float16)a.x; p0[1] = (_Float16)a.y;
    h2 p1; p1[0] = (_Float16)a.z; p1[1] = (_Float16)a.w;
    h2 p2; p2[0] = (_Float16)b.x; p2[1] = (_Float16)b.y;
    h2 p3; p3[0] = (_Float16)b.z; p3[1] = (_Float16)b.w;
    uint4 v;
    v.x = __builtin_bit_cast(unsigned, p0);
    v.y = __builtin_bit_cast(unsigned, p1);
    v.z = __builtin_bit_cast(unsigned, p2);
    v.w = __builtin_bit_cast(unsigned, p3);
    hin4[idx] = v;
}

// Phase 2: B-fragment prep. WB[k][nt][lane][q] =
// f16(W_k[8*(lane>>4)+q][nt*16+(lane&15)]).
__global__ __launch_bounds__(256) void wprep_kernel(const float* __restrict__ kern,
                                                    unsigned short* __restrict__ wb) {
    const int idx = blockIdx.x * 256 + threadIdx.x;   // 0..27647
    const int q  = idx & 7;
    const int l  = (idx >> 3) & 63;
    const int nt = (idx >> 9) & 1;
    const int k  = idx >> 10;
    const int kin = 8 * (l >> 4) + q;
    const int col = nt * 16 + (l & 15);
    const float w = kern[k * 1024 + kin * 32 + col];
    wb[idx] = __builtin_bit_cast(unsigned short, (_Float16)w);
}

// Phase 3: bin entries into (bucket,k) sub-buckets (verified in R4).
// payload = (in_row << 10) | (out_row & 1023)
__global__ __launch_bounds__(256) void bin_kernel(const int* __restrict__ in_map,
                                                  const int* __restrict__ out_map,
                                                  int* __restrict__ gcur,
                                                  int* __restrict__ subbuf) {
    __shared__ int lh[NB];
    const int t = threadIdx.x;
    lh[t] = 0;
    __syncthreads();

    const int k = (blockIdx.x * 4096) >> 17;
    int4 ivv[4], ovv[4];
    #pragma unroll
    for (int j = 0; j < 4; ++j) {
        const int i4 = blockIdx.x * 1024 + j * 256 + t;
        ivv[j] = ((const int4*)in_map)[i4];
        ovv[j] = ((const int4*)out_map)[i4];
    }
    #pragma unroll
    for (int j = 0; j < 4; ++j) {
        atomicAdd(&lh[ovv[j].x >> 10], 1);
        atomicAdd(&lh[ovv[j].y >> 10], 1);
        atomicAdd(&lh[ovv[j].z >> 10], 1);
        atomicAdd(&lh[ovv[j].w >> 10], 1);
    }
    __syncthreads();
    {
        const int c = lh[t];
        int base = 0;
        if (c > 0) base = atomicAdd(&gcur[t * K_VOL + k], c);
        __syncthreads();
        lh[t] = base;
    }
    __syncthreads();

    #pragma unroll
    for (int j = 0; j < 4; ++j) {
        int4 I = ivv[j], O = ovv[j];
        {
            const int b = O.x >> 10, p = (I.x << 10) | (O.x & 1023);
            const int pos = atomicAdd(&lh[b], 1);
            if (pos < SCAP) subbuf[(b * K_VOL + k) * SCAP + pos] = p;
        }
        {
            const int b = O.y >> 10, p = (I.y << 10) | (O.y & 1023);
            const int pos = atomicAdd(&lh[b], 1);
            if (pos < SCAP) subbuf[(b * K_VOL + k) * SCAP + pos] = p;
        }
        {
            const int b = O.z >> 10, p = (I.z << 10) | (O.z & 1023);
            const int pos = atomicAdd(&lh[b], 1);
            if (pos < SCAP) subbuf[(b * K_VOL + k) * SCAP + pos] = p;
        }
        {
            const int b = O.w >> 10, p = (I.w << 10) | (O.w & 1023);
            const int pos = atomicAdd(&lh[b], 1);
            if (pos < SCAP) subbuf[(b * K_VOL + k) * SCAP + pos] = p;
        }
    }
}

// Phase 4: compute. 4096 blocks x 256 thr (4 waves). Block = 64 out-rows;
// wave = 16 out-rows, accumulator in registers across all k. No atomics on data.
__global__ __launch_bounds__(256) void compute_kernel(
    const unsigned short* __restrict__ hin,
    const unsigned short* __restrict__ wb,
    const float* __restrict__ bias,
    const int*  __restrict__ gcur,
    const int*  __restrict__ subbuf,
    float* __restrict__ out)
{
    __shared__ int sub[4][SUBCAP];   // per-wave entry lists for current k
    __shared__ int scnt[4];

    const int t      = threadIdx.x;
    const int l      = t & 63;
    const int w      = t >> 6;       // wave 0..3
    const int lane16 = l & 15;
    const int seg    = l >> 4;       // 0..3

    const int b = blockIdx.x >> 4;   // bin bucket (1024 rows)
    const int q = blockIdx.x & 15;   // 64-row window within bucket

    const int SENT = N_VOX << 4;     // sentinel -> zero row, lr=0
    f32x4 acc0 = {0.f, 0.f, 0.f, 0.f};
    f32x4 acc1 = {0.f, 0.f, 0.f, 0.f};

    for (int k = 0; k < K_VOL; ++k) {
        if (t < 4) scnt[t] = 0;
        __syncthreads();

        const int nk = min(gcur[b * K_VOL + k], SCAP);
        const int* list = subbuf + (b * K_VOL + k) * SCAP;

        // B fragments for W_k (issued early; latency hides under partition).
        const uint4* wp = (const uint4*)wb + (k * 2) * 64 + l;
        const h8 B0 = __builtin_bit_cast(h8, wp[0]);
        const h8 B1 = __builtin_bit_cast(h8, wp[64]);

        // Partition this bucket's k-list into the block's 4 wave sub-lists.
        for (int base = 0; base < nk; base += 256) {
            const int j = base + t;
            if (j < nk) {
                const int e   = list[j];
                const int o10 = e & 1023;
                const int g64 = o10 >> 4;              // bucket16 within bucket: 0..63
                if ((g64 >> 2) == q) {
                    const int wv  = g64 & 3;
                    const int pos = atomicAdd(&scnt[wv], 1);   // few lanes; tiny
                    if (pos < SUBCAP) sub[wv][pos] = ((e >> 10) << 4) | (o10 & 15);
                }
            }
        }
        __syncthreads();

        const int n = min(scnt[w], SUBCAP);
        for (int base = 0; base < n; base += 16) {
            // A-tile: row lane16 = entry (base+lane16), k-chunk seg*8..+7.
            const int slot = base + lane16;
            int es = (slot < n) ? sub[w][slot] : SENT;
            const uint4 a4 = *(const uint4*)(hin + (size_t)(es >> 4) * 32 + (seg << 3));
            const h8 A = __builtin_bit_cast(h8, a4);

            f32x4 ce0 = {0.f, 0.f, 0.f, 0.f};
            f32x4 ce1 = {0.f, 0.f, 0.f, 0.f};
            ce0 = mfma16x16x32(A, B0, ce0);      // C_e[entry][col 0-15]
            ce1 = mfma16x16x32(A, B1, ce1);      // C_e[entry][col 16-31]

            // P[row=lane16][e=seg*4+j] = (lr(e) == lane16), zero for e >= n.
            const int  pb = base + (seg << 2);
            const int4 e4 = *(const int4*)&sub[w][pb];
            h4 P;
            P[0] = (pb + 0 < n && (e4.x & 15) == lane16) ? (_Float16)1 : (_Float16)0;
            P[1] = (pb + 1 < n && (e4.y & 15) == lane16) ? (_Float16)1 : (_Float16)0;
            P[2] = (pb + 2 < n && (e4.z & 15) == lane16) ? (_Float16)1 : (_Float16)0;
            P[3] = (pb + 3 < n && (e4.w & 15) == lane16) ? (_Float16)1 : (_Float16)0;

            // C_e fragment layout == B fragment layout of 16x16x16 -> pure lane-local cast.
            h4 b0, b1;
            b0[0] = (_Float16)ce0[0]; b0[1] = (_Float16)ce0[1];
            b0[2] = (_Float16)ce0[2]; b0[3] = (_Float16)ce0[3];
            b1[0] = (_Float16)ce1[0]; b1[1] = (_Float16)ce1[1];
            b1[2] = (_Float16)ce1[2]; b1[3] = (_Float16)ce1[3];

            acc0 = mfma16x16x16(P, b0, acc0);    // acc[row][col 0-15]
            acc1 = mfma16x16x16(P, b1, acc1);    // acc[row][col 16-31]
        }
        __syncthreads();
    }

    // Store: acc row = seg*4+j, col = lane16 (+16). Bias fused.
    const int rowbase = blockIdx.x * 64 + w * 16 + seg * 4;
    const float bv0 = bias[lane16];
    const float bv1 = bias[16 + lane16];
    #pragma unroll
    for (int j = 0; j < 4; ++j) {
        out[(size_t)(rowbase + j) * 32 + lane16]      = acc0[j] + bv0;
        out[(size_t)(rowbase + j) * 32 + 16 + lane16] = acc1[j] + bv1;
    }
}

extern "C" void kernel_launch(void* const* d_in, const int* in_sizes, int n_in,
                              void* d_out, int out_size, void* d_ws, size_t ws_size,
                              hipStream_t stream) {
    const float* input   = (const float*)d_in[0];
    const float* kernel  = (const float*)d_in[1];
    const float* bias    = (const float*)d_in[2];
    const int*   in_map  = (const int*)d_in[3];
    const int*   out_map = (const int*)d_in[4];
    float* out = (float*)d_out;

    char* ws = (char*)d_ws;
    int* gcur            = (int*)(ws + WS_GCUR);
    unsigned short* wbuf = (unsigned short*)(ws + WS_WB);
    unsigned short* hin  = (unsigned short*)(ws + WS_HIN);
    int* subbuf          = (int*)(ws + WS_SUB);

    (void)hipMemsetAsync(gcur, 0, NB * K_VOL * sizeof(int), stream);
    convert_kernel<<<4097, 256, 0, stream>>>(input, (uint4*)hin);
    wprep_kernel  <<<108,  256, 0, stream>>>(kernel, wbuf);
    bin_kernel    <<<E_TOT / 4096, 256, 0, stream>>>(in_map, out_map, gcur, subbuf);
    compute_kernel<<<4096, 256, 0, stream>>>(hin, wbuf, bias, gcur, subbuf, out);
}

// Round 7
// 231.371 us; speedup vs baseline: 3.1359x; 1.0491x over previous
//
#include <hip/hip_runtime.h>

// Sparse conv, atomic-free compute:
//   bin entries by (bucket=out>>10, k); compute: 1 block (1024 thr, 16 waves) per bucket.
//   Wave owns 64 out-rows (4 x 16-row windows), acc in registers for all 27 k.
//   Per k: block scans bucket k-list once -> 64 LDS window sub-lists; per window:
//   A-tile = gathered f16 rows (exec-masked), C_e = A @ W_k (2x mfma_16x16x32_f16),
//   scatter acc += P @ f16(C_e) (mfma_16x16x16f16, P = 0/1 row-assignment).
// N=262144, M=131072 (2^17), K=27, C_in=C_out=32. fp32 in/out, f16 internal.

constexpr int N_VOX   = 262144;
constexpr int M_PAIRS = 131072;
constexpr int K_VOL   = 27;
constexpr int E_TOT   = K_VOL * M_PAIRS;   // 3538944
constexpr int NB      = 256;               // bin buckets (1024 out-rows each)
constexpr int SCAP    = 640;               // per-(bucket,k) capacity (mean 512)
constexpr int SUBCAP  = 32;                // per-(window16,k) capacity (mean 8; P(ovf)~1e-5)

typedef _Float16 h2  __attribute__((ext_vector_type(2)));
typedef _Float16 h4  __attribute__((ext_vector_type(4)));
typedef _Float16 h8  __attribute__((ext_vector_type(8)));
typedef float    f32x4 __attribute__((ext_vector_type(4)));

// ---- workspace layout (bytes) ----
constexpr size_t WS_GCUR = 0;                      // int[NB*27] = 27648 B
constexpr size_t WS_WB   = 64 * 1024;              // f16 B-frags: 27*2*64*8 = 55296 B
constexpr size_t WS_HIN  = (size_t)1 << 20;        // ushort[N*32] : 16 MB
constexpr size_t WS_SUB  = (size_t)18 << 20;       // int[NB*27*SCAP] : 17.7 MB

__device__ inline f32x4 mfma16x16x32(h8 a, h8 b, f32x4 c) {
    return __builtin_amdgcn_mfma_f32_16x16x32_f16(a, b, c, 0, 0, 0);
}
__device__ inline f32x4 mfma16x16x16(h4 a, h4 b, f32x4 c) {
    return __builtin_amdgcn_mfma_f32_16x16x16f16(a, b, c, 0, 0, 0);
}

// Phase 1: input f32 -> f16 rows.
__global__ __launch_bounds__(256) void convert_kernel(const float* __restrict__ in,
                                                      uint4* __restrict__ hin4) {
    const int idx = blockIdx.x * 256 + threadIdx.x;   // 0 .. 2^20-1
    const float4* in4 = (const float4*)in;
    const float4 a = in4[2 * idx];
    const float4 b = in4[2 * idx + 1];
    h2 p0; p0[0] = (_Float16)a.x; p0[1] = (_Float16)a.y;
    h2 p1; p1[0] = (_Float16)a.z; p1[1] = (_Float16)a.w;
    h2 p2; p2[0] = (_Float16)b.x; p2[1] = (_Float16)b.y;
    h2 p3; p3[0] = (_Float16)b.z; p3[1] = (_Float16)b.w;
    uint4 v;
    v.x = __builtin_bit_cast(unsigned, p0);
    v.y = __builtin_bit_cast(unsigned, p1);
    v.z = __builtin_bit_cast(unsigned, p2);
    v.w = __builtin_bit_cast(unsigned, p3);
    hin4[idx] = v;
}

// Phase 2: B-fragment prep. WB[k][nt][lane][q] = f16(W_k[8*(lane>>4)+q][nt*16+(lane&15)]).
__global__ __launch_bounds__(256) void wprep_kernel(const float* __restrict__ kern,
                                                    unsigned short* __restrict__ wb) {
    const int idx = blockIdx.x * 256 + threadIdx.x;   // 0..27647
    const int q  = idx & 7;
    const int l  = (idx >> 3) & 63;
    const int nt = (idx >> 9) & 1;
    const int k  = idx >> 10;
    const int kin = 8 * (l >> 4) + q;
    const int col = nt * 16 + (l & 15);
    const float w = kern[k * 1024 + kin * 32 + col];
    wb[idx] = __builtin_bit_cast(unsigned short, (_Float16)w);
}

// Phase 3: bin entries into (bucket,k) sub-buckets (verified R4/R6).
// payload = (in_row << 10) | (out_row & 1023)
__global__ __launch_bounds__(256) void bin_kernel(const int* __restrict__ in_map,
                                                  const int* __restrict__ out_map,
                                                  int* __restrict__ gcur,
                                                  int* __restrict__ subbuf) {
    __shared__ int lh[NB];
    const int t = threadIdx.x;
    lh[t] = 0;
    __syncthreads();

    const int k = (blockIdx.x * 4096) >> 17;
    int4 ivv[4], ovv[4];
    #pragma unroll
    for (int j = 0; j < 4; ++j) {
        const int i4 = blockIdx.x * 1024 + j * 256 + t;
        ivv[j] = ((const int4*)in_map)[i4];
        ovv[j] = ((const int4*)out_map)[i4];
    }
    #pragma unroll
    for (int j = 0; j < 4; ++j) {
        atomicAdd(&lh[ovv[j].x >> 10], 1);
        atomicAdd(&lh[ovv[j].y >> 10], 1);
        atomicAdd(&lh[ovv[j].z >> 10], 1);
        atomicAdd(&lh[ovv[j].w >> 10], 1);
    }
    __syncthreads();
    {
        const int c = lh[t];
        int base = 0;
        if (c > 0) base = atomicAdd(&gcur[t * K_VOL + k], c);
        __syncthreads();
        lh[t] = base;
    }
    __syncthreads();

    #pragma unroll
    for (int j = 0; j < 4; ++j) {
        int4 I = ivv[j], O = ovv[j];
        {
            const int b = O.x >> 10, p = (I.x << 10) | (O.x & 1023);
            const int pos = atomicAdd(&lh[b], 1);
            if (pos < SCAP) subbuf[(b * K_VOL + k) * SCAP + pos] = p;
        }
        {
            const int b = O.y >> 10, p = (I.y << 10) | (O.y & 1023);
            const int pos = atomicAdd(&lh[b], 1);
            if (pos < SCAP) subbuf[(b * K_VOL + k) * SCAP + pos] = p;
        }
        {
            const int b = O.z >> 10, p = (I.z << 10) | (O.z & 1023);
            const int pos = atomicAdd(&lh[b], 1);
            if (pos < SCAP) subbuf[(b * K_VOL + k) * SCAP + pos] = p;
        }
        {
            const int b = O.w >> 10, p = (I.w << 10) | (O.w & 1023);
            const int pos = atomicAdd(&lh[b], 1);
            if (pos < SCAP) subbuf[(b * K_VOL + k) * SCAP + pos] = p;
        }
    }
}

// Phase 4: compute. 256 blocks (1/bucket) x 1024 thr (16 waves x 64 rows).
__global__ __launch_bounds__(1024) void compute_kernel(
    const unsigned short* __restrict__ hin,
    const unsigned short* __restrict__ wb,
    const float* __restrict__ bias,
    const int*  __restrict__ gcur,
    const int*  __restrict__ subbuf,
    float* __restrict__ out)
{
    __shared__ int sub[64][SUBCAP];   // per-window16 entry lists for current k (8 KB)
    __shared__ int scnt[64];

    const int t      = threadIdx.x;
    const int l      = t & 63;
    const int w      = t >> 6;       // wave 0..15 -> rows w*64 .. w*64+63
    const int lane16 = l & 15;
    const int seg    = l >> 4;       // 0..3
    const int b      = blockIdx.x;   // bucket (1024 rows)

    f32x4 acc0[4], acc1[4];
    #pragma unroll
    for (int s = 0; s < 4; ++s) {
        acc0[s] = (f32x4){0.f, 0.f, 0.f, 0.f};
        acc1[s] = (f32x4){0.f, 0.f, 0.f, 0.f};
    }

    for (int k = 0; k < K_VOL; ++k) {
        if (t < 64) scnt[t] = 0;
        __syncthreads();

        const int nk = min(gcur[b * K_VOL + k], SCAP);
        const int* list = subbuf + (b * K_VOL + k) * SCAP;

        // B fragments for W_k (issue early; reused by all tiles this k).
        const uint4* wp = (const uint4*)wb + (k * 2) * 64 + l;
        const h8 B0 = __builtin_bit_cast(h8, wp[0]);
        const h8 B1 = __builtin_bit_cast(h8, wp[64]);

        // Cooperative partition: one pass (nk <= 640 < 1024).
        if (t < nk) {
            const int e   = list[t];
            const int o10 = e & 1023;
            const int win = o10 >> 4;                      // 0..63
            const int pos = atomicAdd(&scnt[win], 1);
            if (pos < SUBCAP) sub[win][pos] = ((e >> 10) << 4) | (o10 & 15);
        }
        __syncthreads();

        #pragma unroll
        for (int s = 0; s < 4; ++s) {
            const int win = w * 4 + s;
            const int n   = min(scnt[win], SUBCAP);
            for (int base = 0; base < n; base += 16) {
                // A-tile row lane16 = entry (base+lane16); invalid lanes: A = 0 (no load).
                const int slot = base + lane16;
                h8 A = {};
                if (slot < n) {
                    const int es = sub[win][slot];
                    const uint4 a4 = *(const uint4*)(hin + (size_t)(es >> 4) * 32 + (seg << 3));
                    A = __builtin_bit_cast(h8, a4);
                }

                f32x4 ce0 = {0.f, 0.f, 0.f, 0.f};
                f32x4 ce1 = {0.f, 0.f, 0.f, 0.f};
                ce0 = mfma16x16x32(A, B0, ce0);      // C_e[entry][col 0-15]
                ce1 = mfma16x16x32(A, B1, ce1);      // C_e[entry][col 16-31]

                // P[row=lane16][e=seg*4+j] = (lr(e) == lane16), 0 for e >= n.
                const int  pb = base + (seg << 2);
                const int4 e4 = *(const int4*)&sub[win][pb & (SUBCAP - 4)];
                h4 P;
                P[0] = (pb + 0 < n && (e4.x & 15) == lane16) ? (_Float16)1 : (_Float16)0;
                P[1] = (pb + 1 < n && (e4.y & 15) == lane16) ? (_Float16)1 : (_Float16)0;
                P[2] = (pb + 2 < n && (e4.z & 15) == lane16) ? (_Float16)1 : (_Float16)0;
                P[3] = (pb + 3 < n && (e4.w & 15) == lane16) ? (_Float16)1 : (_Float16)0;

                // C_e fragment layout == B fragment layout of 16x16x16 (lane-local cast).
                h4 b0, b1;
                b0[0] = (_Float16)ce0[0]; b0[1] = (_Float16)ce0[1];
                b0[2] = (_Float16)ce0[2]; b0[3] = (_Float16)ce0[3];
                b1[0] = (_Float16)ce1[0]; b1[1] = (_Float16)ce1[1];
                b1[2] = (_Float16)ce1[2]; b1[3] = (_Float16)ce1[3];

                acc0[s] = mfma16x16x16(P, b0, acc0[s]);
                acc1[s] = mfma16x16x16(P, b1, acc1[s]);
            }
        }
        __syncthreads();
    }

    // Store: window w*4+s, row seg*4+j, col lane16 (+16). Bias fused.
    const float bv0 = bias[lane16];
    const float bv1 = bias[16 + lane16];
    #pragma unroll
    for (int s = 0; s < 4; ++s) {
        const int rowbase = b * 1024 + (w * 4 + s) * 16 + seg * 4;
        #pragma unroll
        for (int j = 0; j < 4; ++j) {
            out[(size_t)(rowbase + j) * 32 + lane16]      = acc0[s][j] + bv0;
            out[(size_t)(rowbase + j) * 32 + 16 + lane16] = acc1[s][j] + bv1;
        }
    }
}

extern "C" void kernel_launch(void* const* d_in, const int* in_sizes, int n_in,
                              void* d_out, int out_size, void* d_ws, size_t ws_size,
                              hipStream_t stream) {
    const float* input   = (const float*)d_in[0];
    const float* kernel  = (const float*)d_in[1];
    const float* bias    = (const float*)d_in[2];
    const int*   in_map  = (const int*)d_in[3];
    const int*   out_map = (const int*)d_in[4];
    float* out = (float*)d_out;

    char* ws = (char*)d_ws;
    int* gcur            = (int*)(ws + WS_GCUR);
    unsigned short* wbuf = (unsigned short*)(ws + WS_WB);
    unsigned short* hin  = (unsigned short*)(ws + WS_HIN);
    int* subbuf          = (int*)(ws + WS_SUB);

    (void)hipMemsetAsync(gcur, 0, NB * K_VOL * sizeof(int), stream);
    convert_kernel<<<4096, 256, 0, stream>>>(input, (uint4*)hin);
    wprep_kernel  <<<108,  256, 0, stream>>>(kernel, wbuf);
    bin_kernel    <<<E_TOT / 4096, 256, 0, stream>>>(in_map, out_map, gcur, subbuf);
    compute_kernel<<<NB, 1024, 0, stream>>>(hin, wbuf, bias, gcur, subbuf, out);
}

// Round 8
// 206.006 us; speedup vs baseline: 3.5221x; 1.1231x over previous
//
#include <hip/hip_runtime.h>

// Sparse conv, atomic-free compute, software-pipelined:
//   bin entries by (bucket=out>>9, k); compute: 1 block (512 thr, 8 waves) per bucket,
//   2 blocks/CU. Wave owns 64 out-rows (4 x 16-row windows), acc in registers all 27 k.
//   Per k (ONE barrier): prefetch k+1 list to regs; batched masked gathers for 4 windows;
//   C_e = A @ W_k (2x mfma_16x16x32_f16); scatter acc += P @ f16(C_e) (mfma_16x16x16f16);
//   then LDS-fill k+1 sub-lists (double-buffered, no extra barrier).
// N=262144, M=131072 (2^17), K=27, C_in=C_out=32. fp32 in/out, f16 internal.

constexpr int N_VOX   = 262144;
constexpr int M_PAIRS = 131072;
constexpr int K_VOL   = 27;
constexpr int E_TOT   = K_VOL * M_PAIRS;   // 3538944
constexpr int NB      = 512;               // buckets (512 out-rows each)
constexpr int NWIN    = 32;                // 16-row windows per bucket
constexpr int SCAP    = 336;               // per-(bucket,k) capacity (mean 256, +5σ)
constexpr int SUBCAP  = 32;                // per-(window,k) capacity (mean 8)

typedef _Float16 h2  __attribute__((ext_vector_type(2)));
typedef _Float16 h4  __attribute__((ext_vector_type(4)));
typedef _Float16 h8  __attribute__((ext_vector_type(8)));
typedef float    f32x4 __attribute__((ext_vector_type(4)));

// ---- workspace layout (bytes) ----
constexpr size_t WS_GCUR = 0;                      // int[NB*27] = 55296 B
constexpr size_t WS_WB   = 64 * 1024;              // f16 B-frags: 27*2*64*8 = 55296 B
constexpr size_t WS_HIN  = (size_t)1 << 20;        // ushort[N*32] : 16 MB
constexpr size_t WS_SUB  = (size_t)18 << 20;       // int[NB*27*SCAP] : 18.6 MB

__device__ inline f32x4 mfma16x16x32(h8 a, h8 b, f32x4 c) {
    return __builtin_amdgcn_mfma_f32_16x16x32_f16(a, b, c, 0, 0, 0);
}
__device__ inline f32x4 mfma16x16x16(h4 a, h4 b, f32x4 c) {
    return __builtin_amdgcn_mfma_f32_16x16x16f16(a, b, c, 0, 0, 0);
}

// Phase 1: input f32 -> f16 rows.
__global__ __launch_bounds__(256) void convert_kernel(const float* __restrict__ in,
                                                      uint4* __restrict__ hin4) {
    const int idx = blockIdx.x * 256 + threadIdx.x;   // 0 .. 2^20-1
    const float4* in4 = (const float4*)in;
    const float4 a = in4[2 * idx];
    const float4 b = in4[2 * idx + 1];
    h2 p0; p0[0] = (_Float16)a.x; p0[1] = (_Float16)a.y;
    h2 p1; p1[0] = (_Float16)a.z; p1[1] = (_Float16)a.w;
    h2 p2; p2[0] = (_Float16)b.x; p2[1] = (_Float16)b.y;
    h2 p3; p3[0] = (_Float16)b.z; p3[1] = (_Float16)b.w;
    uint4 v;
    v.x = __builtin_bit_cast(unsigned, p0);
    v.y = __builtin_bit_cast(unsigned, p1);
    v.z = __builtin_bit_cast(unsigned, p2);
    v.w = __builtin_bit_cast(unsigned, p3);
    hin4[idx] = v;
}

// Phase 2: B-fragment prep. WB[k][nt][lane][q] = f16(W_k[8*(lane>>4)+q][nt*16+(lane&15)]).
__global__ __launch_bounds__(256) void wprep_kernel(const float* __restrict__ kern,
                                                    unsigned short* __restrict__ wb) {
    const int idx = blockIdx.x * 256 + threadIdx.x;   // 0..27647
    const int q  = idx & 7;
    const int l  = (idx >> 3) & 63;
    const int nt = (idx >> 9) & 1;
    const int k  = idx >> 10;
    const int kin = 8 * (l >> 4) + q;
    const int col = nt * 16 + (l & 15);
    const float w = kern[k * 1024 + kin * 32 + col];
    wb[idx] = __builtin_bit_cast(unsigned short, (_Float16)w);
}

// Phase 3: bin entries into (bucket,k) sub-buckets. payload = (in<<9)|(out&511).
__global__ __launch_bounds__(256) void bin_kernel(const int* __restrict__ in_map,
                                                  const int* __restrict__ out_map,
                                                  int* __restrict__ gcur,
                                                  int* __restrict__ subbuf) {
    __shared__ int lh[NB];
    const int t = threadIdx.x;
    lh[t] = 0; lh[t + 256] = 0;
    __syncthreads();

    const int k = (blockIdx.x * 4096) >> 17;
    int4 ivv[4], ovv[4];
    #pragma unroll
    for (int j = 0; j < 4; ++j) {
        const int i4 = blockIdx.x * 1024 + j * 256 + t;
        ivv[j] = ((const int4*)in_map)[i4];
        ovv[j] = ((const int4*)out_map)[i4];
    }
    #pragma unroll
    for (int j = 0; j < 4; ++j) {
        atomicAdd(&lh[ovv[j].x >> 9], 1);
        atomicAdd(&lh[ovv[j].y >> 9], 1);
        atomicAdd(&lh[ovv[j].z >> 9], 1);
        atomicAdd(&lh[ovv[j].w >> 9], 1);
    }
    __syncthreads();
    {
        const int c0 = lh[t], c1 = lh[t + 256];
        int b0 = 0, b1 = 0;
        if (c0 > 0) b0 = atomicAdd(&gcur[t * K_VOL + k], c0);
        if (c1 > 0) b1 = atomicAdd(&gcur[(t + 256) * K_VOL + k], c1);
        __syncthreads();
        lh[t] = b0; lh[t + 256] = b1;
    }
    __syncthreads();

    #pragma unroll
    for (int j = 0; j < 4; ++j) {
        int4 I = ivv[j], O = ovv[j];
        {
            const int b = O.x >> 9, p = (I.x << 9) | (O.x & 511);
            const int pos = atomicAdd(&lh[b], 1);
            if (pos < SCAP) subbuf[(b * K_VOL + k) * SCAP + pos] = p;
        }
        {
            const int b = O.y >> 9, p = (I.y << 9) | (O.y & 511);
            const int pos = atomicAdd(&lh[b], 1);
            if (pos < SCAP) subbuf[(b * K_VOL + k) * SCAP + pos] = p;
        }
        {
            const int b = O.z >> 9, p = (I.z << 9) | (O.z & 511);
            const int pos = atomicAdd(&lh[b], 1);
            if (pos < SCAP) subbuf[(b * K_VOL + k) * SCAP + pos] = p;
        }
        {
            const int b = O.w >> 9, p = (I.w << 9) | (O.w & 511);
            const int pos = atomicAdd(&lh[b], 1);
            if (pos < SCAP) subbuf[(b * K_VOL + k) * SCAP + pos] = p;
        }
    }
}

// Phase 4: compute. 512 blocks (1/bucket) x 512 thr (8 waves x 64 rows), 2 blocks/CU.
__global__ __launch_bounds__(512, 4) void compute_kernel(
    const unsigned short* __restrict__ hin,
    const unsigned short* __restrict__ wb,
    const float* __restrict__ bias,
    const int*  __restrict__ gcur,
    const int*  __restrict__ subbuf,
    float* __restrict__ out)
{
    __shared__ int sub[2][NWIN][SUBCAP];   // double-buffered window lists (8 KB)
    __shared__ int scnt[K_VOL][NWIN];      // persistent per-k counters (3.4 KB)

    const int t      = threadIdx.x;
    const int l      = t & 63;
    const int w      = t >> 6;       // wave 0..7 -> windows w*4 .. w*4+3
    const int lane16 = l & 15;
    const int seg    = l >> 4;       // 0..3
    const int b      = blockIdx.x;   // bucket (512 rows)

    for (int i = t; i < K_VOL * NWIN; i += 512) ((int*)scnt)[i] = 0;

    // Prologue: prefetch + fill k=0 into buffer 0.
    const int nk0 = min(gcur[b * K_VOL], SCAP);
    int e0 = 0;
    const bool hv0 = (t < nk0);
    if (hv0) e0 = subbuf[(b * K_VOL) * SCAP + t];
    __syncthreads();                 // scnt zeroing visible
    if (hv0) {
        const int o9 = e0 & 511, win = o9 >> 4;
        const int pos = atomicAdd(&scnt[0][win], 1);
        if (pos < SUBCAP) sub[0][win][pos] = ((e0 >> 9) << 4) | (o9 & 15);
    }

    f32x4 acc0[4], acc1[4];
    #pragma unroll
    for (int s = 0; s < 4; ++s) {
        acc0[s] = (f32x4){0.f, 0.f, 0.f, 0.f};
        acc1[s] = (f32x4){0.f, 0.f, 0.f, 0.f};
    }

    for (int k = 0; k < K_VOL; ++k) {
        __syncthreads();             // fill(k) complete; compute(k-1) complete

        // Register-prefetch k+1 list (latency hides under compute below).
        int e2 = 0, nk2 = 0;
        bool hv2 = false;
        if (k + 1 < K_VOL) {
            nk2 = min(gcur[b * K_VOL + k + 1], SCAP);
            hv2 = (t < nk2);
            if (hv2) e2 = subbuf[(b * K_VOL + k + 1) * SCAP + t];
        }

        // B fragments for W_k.
        const uint4* wp = (const uint4*)wb + (k * 2) * 64 + l;
        const h8 B0 = __builtin_bit_cast(h8, wp[0]);
        const h8 B1 = __builtin_bit_cast(h8, wp[64]);
        const int buf = k & 1;

        // Batched first-tile gathers for the wave's 4 windows.
#define WLOAD(S, NS, AS)                                                        \
        const int win##S = (w << 2) + S;                                        \
        const int NS = min(scnt[k][win##S], SUBCAP);                            \
        h8 AS = {};                                                             \
        if (lane16 < NS) {                                                      \
            const int es = sub[buf][win##S][lane16];                            \
            AS = __builtin_bit_cast(h8,                                         \
                 *(const uint4*)(hin + (size_t)(es >> 4) * 32 + (seg << 3)));   \
        }
        WLOAD(0, n0, A0)
        WLOAD(1, n1, A1)
        WLOAD(2, n2, A2)
        WLOAD(3, n3, A3)
#undef WLOAD

#define WCOMP(S, NS, AS)                                                        \
        {                                                                       \
            f32x4 ce0 = {0.f,0.f,0.f,0.f}, ce1 = {0.f,0.f,0.f,0.f};             \
            ce0 = mfma16x16x32(AS, B0, ce0);                                    \
            ce1 = mfma16x16x32(AS, B1, ce1);                                    \
            const int4 e4 = *(const int4*)&sub[buf][win##S][seg << 2];          \
            h4 P;                                                               \
            P[0] = ((seg<<2)+0 < NS && (e4.x & 15) == lane16) ? (_Float16)1 : (_Float16)0; \
            P[1] = ((seg<<2)+1 < NS && (e4.y & 15) == lane16) ? (_Float16)1 : (_Float16)0; \
            P[2] = ((seg<<2)+2 < NS && (e4.z & 15) == lane16) ? (_Float16)1 : (_Float16)0; \
            P[3] = ((seg<<2)+3 < NS && (e4.w & 15) == lane16) ? (_Float16)1 : (_Float16)0; \
            h4 c0h, c1h;                                                        \
            c0h[0]=(_Float16)ce0[0]; c0h[1]=(_Float16)ce0[1];                   \
            c0h[2]=(_Float16)ce0[2]; c0h[3]=(_Float16)ce0[3];                   \
            c1h[0]=(_Float16)ce1[0]; c1h[1]=(_Float16)ce1[1];                   \
            c1h[2]=(_Float16)ce1[2]; c1h[3]=(_Float16)ce1[3];                   \
            acc0[S] = mfma16x16x16(P, c0h, acc0[S]);                            \
            acc1[S] = mfma16x16x16(P, c1h, acc1[S]);                            \
            if (NS > 16) {                                                      \
                for (int base = 16; base < NS; base += 16) {                    \
                    const int slot = base + lane16;                             \
                    h8 At = {};                                                 \
                    if (slot < NS) {                                            \
                        const int es = sub[buf][win##S][slot];                  \
                        At = __builtin_bit_cast(h8,                             \
                             *(const uint4*)(hin + (size_t)(es >> 4) * 32 + (seg << 3))); \
                    }                                                           \
                    f32x4 d0 = {0.f,0.f,0.f,0.f}, d1 = {0.f,0.f,0.f,0.f};       \
                    d0 = mfma16x16x32(At, B0, d0);                              \
                    d1 = mfma16x16x32(At, B1, d1);                              \
                    const int pb = base + (seg << 2);                           \
                    const int4 f4 = *(const int4*)&sub[buf][win##S][pb];        \
                    h4 Q;                                                       \
                    Q[0] = (pb+0 < NS && (f4.x & 15) == lane16) ? (_Float16)1 : (_Float16)0; \
                    Q[1] = (pb+1 < NS && (f4.y & 15) == lane16) ? (_Float16)1 : (_Float16)0; \
                    Q[2] = (pb+2 < NS && (f4.z & 15) == lane16) ? (_Float16)1 : (_Float16)0; \
                    Q[3] = (pb+3 < NS && (f4.w & 15) == lane16) ? (_Float16)1 : (_Float16)0; \
                    h4 d0h, d1h;                                                \
                    d0h[0]=(_Float16)d0[0]; d0h[1]=(_Float16)d0[1];             \
                    d0h[2]=(_Float16)d0[2]; d0h[3]=(_Float16)d0[3];             \
                    d1h[0]=(_Float16)d1[0]; d1h[1]=(_Float16)d1[1];             \
                    d1h[2]=(_Float16)d1[2]; d1h[3]=(_Float16)d1[3];             \
                    acc0[S] = mfma16x16x16(Q, d0h, acc0[S]);                    \
                    acc1[S] = mfma16x16x16(Q, d1h, acc1[S]);                    \
                }                                                               \
            }                                                                   \
        }
        WCOMP(0, n0, A0)
        WCOMP(1, n1, A1)
        WCOMP(2, n2, A2)
        WCOMP(3, n3, A3)
#undef WCOMP

        // Fill k+1 into the other buffer (no barrier: parity-safe).
        if (hv2) {
            const int o9 = e2 & 511, win = o9 >> 4;
            const int pos = atomicAdd(&scnt[k + 1][win], 1);
            if (pos < SUBCAP) sub[buf ^ 1][win][pos] = ((e2 >> 9) << 4) | (o9 & 15);
        }
    }

    // Store: window w*4+s, row seg*4+j, col lane16 (+16). Bias fused.
    const float bv0 = bias[lane16];
    const float bv1 = bias[16 + lane16];
    #pragma unroll
    for (int s = 0; s < 4; ++s) {
        const int rowbase = b * 512 + (w * 4 + s) * 16 + seg * 4;
        #pragma unroll
        for (int j = 0; j < 4; ++j) {
            out[(size_t)(rowbase + j) * 32 + lane16]      = acc0[s][j] + bv0;
            out[(size_t)(rowbase + j) * 32 + 16 + lane16] = acc1[s][j] + bv1;
        }
    }
}

extern "C" void kernel_launch(void* const* d_in, const int* in_sizes, int n_in,
                              void* d_out, int out_size, void* d_ws, size_t ws_size,
                              hipStream_t stream) {
    const float* input   = (const float*)d_in[0];
    const float* kernel  = (const float*)d_in[1];
    const float* bias    = (const float*)d_in[2];
    const int*   in_map  = (const int*)d_in[3];
    const int*   out_map = (const int*)d_in[4];
    float* out = (float*)d_out;

    char* ws = (char*)d_ws;
    int* gcur            = (int*)(ws + WS_GCUR);
    unsigned short* wbuf = (unsigned short*)(ws + WS_WB);
    unsigned short* hin  = (unsigned short*)(ws + WS_HIN);
    int* subbuf          = (int*)(ws + WS_SUB);

    (void)hipMemsetAsync(gcur, 0, NB * K_VOL * sizeof(int), stream);
    convert_kernel<<<4096, 256, 0, stream>>>(input, (uint4*)hin);
    wprep_kernel  <<<108,  256, 0, stream>>>(kernel, wbuf);
    bin_kernel    <<<E_TOT / 4096, 256, 0, stream>>>(in_map, out_map, gcur, subbuf);
    compute_kernel<<<NB, 512, 0, stream>>>(hin, wbuf, bias, gcur, subbuf, out);
}